// Round 2
// baseline (429.694 us; speedup 1.0000x reference)
//
#include <hip/hip_runtime.h>
#include <math.h>

// VectorQuantizer: N=131072 tokens, K=1024 codes, D=64, fp32.
// Out layout (flat): z_q_st[N*D] | loss | perplexity | indices[N] (as f32)
#define NTOK 131072
#define NEMB 1024
#define DIM  64
#define OUT_LOSS (NTOK * DIM)
#define OUT_PERP (OUT_LOSS + 1)
#define OUT_IDX  (OUT_LOSS + 2)

// ---- numpy fp32 semantics replication helpers -------------------------------
// Square with a scheduling barrier so the compiler cannot contract the
// multiply into a following add (numpy rounds x*x, then adds).
__device__ __forceinline__ float sqb(float x) {
    float y = x * x;
    asm volatile("" : "+v"(y));
    return y;
}

// numpy pairwise_sum for n=64, contiguous: 8 accumulators striding by 8,
// then ((r0+r1)+(r2+r3))+((r4+r5)+(r6+r7)). GET(d) must return element d.
#define NP_PAIRWISE_SQ64(GET, RES)                                     \
    do {                                                               \
        float r0 = sqb(GET(0)), r1 = sqb(GET(1)), r2 = sqb(GET(2)),    \
              r3 = sqb(GET(3)), r4 = sqb(GET(4)), r5 = sqb(GET(5)),    \
              r6 = sqb(GET(6)), r7 = sqb(GET(7));                      \
        _Pragma("unroll")                                              \
        for (int i = 8; i < 64; i += 8) {                              \
            r0 += sqb(GET(i + 0)); r1 += sqb(GET(i + 1));              \
            r2 += sqb(GET(i + 2)); r3 += sqb(GET(i + 3));              \
            r4 += sqb(GET(i + 4)); r5 += sqb(GET(i + 5));              \
            r6 += sqb(GET(i + 6)); r7 += sqb(GET(i + 7));              \
        }                                                              \
        RES = ((r0 + r1) + (r2 + r3)) + ((r4 + r5) + (r6 + r7));       \
    } while (0)

// ws layout: double sse | int counts[NEMB] | float h[NEMB] | int idx[NTOK]

// Kernel 0: h[k] = np.sum(codebook*codebook, axis=-1)[k], bit-exact numpy fp32.
__global__ void vq_prep(const float* __restrict__ cb, float* __restrict__ h) {
    int k = blockIdx.x * blockDim.x + threadIdx.x;
    if (k >= NEMB) return;
    const float* c = cb + k * DIM;
    float hk;
#define GETC(d) (c[d])
    NP_PAIRWISE_SQ64(GETC, hk);
#undef GETC
    h[k] = hk;
}

// Kernel 1: per-token argmin of d_k = fl32(fl32(sz + h_k) - fl32(2*dot_k)),
// first-hit on ties -- replicates np.argmin over the fp32-rounded distance.
__global__ __launch_bounds__(256) void vq_main(
    const float* __restrict__ ze,
    const float* __restrict__ cb,
    const float* __restrict__ h,
    float*       __restrict__ out,
    int*         __restrict__ idx_ws,
    int*         __restrict__ counts) {
    const int t = blockIdx.x * 256 + threadIdx.x;

    float z[DIM];
    const float4* zp4 = (const float4*)(ze + (size_t)t * DIM);
#pragma unroll
    for (int q = 0; q < 16; ++q) {
        float4 v = zp4[q];
        z[4 * q + 0] = v.x; z[4 * q + 1] = v.y;
        z[4 * q + 2] = v.z; z[4 * q + 3] = v.w;
    }

    // sz = np.sum(z*z, axis=-1) bit-exact (pairwise, squares rounded first)
    float sz;
#define GETZ(d) (z[d])
    NP_PAIRWISE_SQ64(GETZ, sz);
#undef GETZ

    float best = INFINITY;
    int bidx = 0;
    for (int k = 0; k < NEMB; ++k) {
        const float4* c4 = (const float4*)(cb + k * DIM);
        float a0 = 0.f, a1 = 0.f, a2 = 0.f, a3 = 0.f;
#pragma unroll
        for (int q = 0; q < 16; ++q) {
            float4 cv = c4[q];
            a0 = fmaf(cv.x, z[4 * q + 0], a0);
            a1 = fmaf(cv.y, z[4 * q + 1], a1);
            a2 = fmaf(cv.z, z[4 * q + 2], a2);
            a3 = fmaf(cv.w, z[4 * q + 3], a3);
        }
        float dot = (a0 + a1) + (a2 + a3);
        float dk = (sz + h[k]) - 2.0f * dot;  // 2*dot exact; fma-contraction harmless
        if (dk < best) { best = dk; bidx = k; }
    }

    out[OUT_IDX + t] = (float)bidx;  // indices as f32, coalesced
    idx_ws[t] = bidx;
    atomicAdd(&counts[bidx], 1);
}

// Kernel 2: coalesced gather z_q_st = codebook[idx], plus fp64 SSE reduction.
// One wave covers exactly one token row (64 lanes == 64 dims): idx uniform,
// codebook row read contiguous, ze read / out write fully coalesced.
__global__ __launch_bounds__(256) void vq_gather(
    const float* __restrict__ ze,
    const float* __restrict__ cb,
    const int*   __restrict__ idx_ws,
    float*       __restrict__ out,
    double*      __restrict__ sse_g) {
    const int base = blockIdx.x * 256 + threadIdx.x;
    const int stride = 2048 * 256;  // grid is 2048 blocks
    double lsse = 0.0;
#pragma unroll
    for (int it = 0; it < 16; ++it) {
        int gid = base + it * stride;
        int n = gid >> 6, d = gid & 63;
        float q = cb[idx_ws[n] * DIM + d];
        float zv = ze[gid];
        out[gid] = q;
        double diff = (double)q - (double)zv;
        lsse = fma(diff, diff, lsse);
    }
#pragma unroll
    for (int off = 32; off > 0; off >>= 1)
        lsse += __shfl_down(lsse, off, 64);
    __shared__ double red[4];
    if ((threadIdx.x & 63) == 0) red[threadIdx.x >> 6] = lsse;
    __syncthreads();
    if (threadIdx.x == 0)
        atomicAdd(sse_g, (red[0] + red[1]) + (red[2] + red[3]));
}

// Kernel 3: finalize loss (= 1.25 * MSE since both loss terms are identical)
// and perplexity from the histogram.
__global__ void vq_finalize(const double* __restrict__ sse_g,
                            const int*    __restrict__ counts,
                            float*        __restrict__ out) {
    __shared__ double red[256];
    int tid = threadIdx.x;
    double local = 0.0;
    for (int k = tid; k < NEMB; k += 256) {
        double p = (double)counts[k] / (double)NTOK;
        local += p * log(p + 1e-10);
    }
    red[tid] = local;
    __syncthreads();
    for (int s = 128; s > 0; s >>= 1) {
        if (tid < s) red[tid] += red[tid + s];
        __syncthreads();
    }
    if (tid == 0) {
        double mse = *sse_g / ((double)NTOK * (double)DIM);
        out[OUT_LOSS] = (float)(1.25 * mse);
        out[OUT_PERP] = (float)exp(-red[0]);
    }
}

extern "C" void kernel_launch(void* const* d_in, const int* in_sizes, int n_in,
                              void* d_out, int out_size, void* d_ws, size_t ws_size,
                              hipStream_t stream) {
    const float* ze = (const float*)d_in[0];
    const float* cb = (const float*)d_in[1];
    float* out = (float*)d_out;

    char* w = (char*)d_ws;
    double* sse    = (double*)w;                       // 8 B
    int*    counts = (int*)(w + 8);                    // 4 KiB
    float*  h      = (float*)(w + 8 + 4096);           // 4 KiB
    int*    idx_ws = (int*)(w + 8 + 4096 + 4096);      // 512 KiB

    // Zero accumulators every launch (ws is poisoned once, never re-poisoned).
    hipMemsetAsync((void*)sse, 0, 8 + 4096, stream);

    vq_prep<<<NEMB / 256, 256, 0, stream>>>(cb, h);
    vq_main<<<NTOK / 256, 256, 0, stream>>>(ze, cb, h, out, idx_ws, counts);
    vq_gather<<<2048, 256, 0, stream>>>(ze, cb, idx_ws, out, sse);
    vq_finalize<<<1, 256, 0, stream>>>(sse, counts, out);
}

// Round 3
// 310.452 us; speedup vs baseline: 1.3841x; 1.3841x over previous
//
#include <hip/hip_runtime.h>
#include <math.h>

// VectorQuantizer: N=131072 tokens, K=1024 codes, D=64, fp32.
// Out layout (flat): z_q_st[N*D] | loss | perplexity | indices[N] (as f32)
#define NTOK 131072
#define NEMB 1024
#define DIM  64
#define OUT_LOSS (NTOK * DIM)
#define OUT_PERP (OUT_LOSS + 1)
#define OUT_IDX  (OUT_LOSS + 2)

#define EPS_FLAG 6e-5f   // screen ambiguity margin (2.3x over derived error bound)

typedef short bf16x8 __attribute__((ext_vector_type(8)));
typedef float f32x4  __attribute__((ext_vector_type(4)));

// ---- numpy fp32 semantics helpers (frozen from round 2 -- PASSED) ----------
__device__ __forceinline__ float sqb(float x) {
    float y = x * x;
    asm volatile("" : "+v"(y));
    return y;
}
// numpy pairwise_sum for n=64 contiguous: 8 accumulators stride 8, then
// ((r0+r1)+(r2+r3))+((r4+r5)+(r6+r7)).
#define NP_PAIRWISE_SQ64(GET, RES)                                     \
    do {                                                               \
        float r0 = sqb(GET(0)), r1 = sqb(GET(1)), r2 = sqb(GET(2)),    \
              r3 = sqb(GET(3)), r4 = sqb(GET(4)), r5 = sqb(GET(5)),    \
              r6 = sqb(GET(6)), r7 = sqb(GET(7));                      \
        _Pragma("unroll")                                              \
        for (int i = 8; i < 64; i += 8) {                              \
            r0 += sqb(GET(i + 0)); r1 += sqb(GET(i + 1));              \
            r2 += sqb(GET(i + 2)); r3 += sqb(GET(i + 3));              \
            r4 += sqb(GET(i + 4)); r5 += sqb(GET(i + 5));              \
            r6 += sqb(GET(i + 6)); r7 += sqb(GET(i + 7));              \
        }                                                              \
        RES = ((r0 + r1) + (r2 + r3)) + ((r4 + r5) + (r6 + r7));       \
    } while (0)

__device__ __forceinline__ unsigned short f2bf_rne(float x) {
    unsigned u = __float_as_uint(x);
    u += 0x7FFFu + ((u >> 16) & 1u);   // round-to-nearest-even
    return (unsigned short)(u >> 16);
}
__device__ __forceinline__ float bf2f(unsigned short b) {
    return __uint_as_float(((unsigned)b) << 16);
}

// ws layout (bytes): 0: sse double | 64: counts int[1024] | 4160: h f32[1024]
//                    8256: ch bf16[1024*64] | 139328: cl bf16[1024*64]

// Kernel 0: h[k] np-exact; ch/cl = bf16 2-way split of (-2*codebook).
__global__ void vq_prep(const float* __restrict__ cb, float* __restrict__ h,
                        unsigned short* __restrict__ ch, unsigned short* __restrict__ cl) {
    int k = blockIdx.x * 256 + threadIdx.x;
    if (k >= NEMB) return;
    float c[64];
    const float4* p = (const float4*)(cb + k * DIM);
#pragma unroll
    for (int q = 0; q < 16; ++q) {
        float4 v = p[q];
        c[4 * q] = v.x; c[4 * q + 1] = v.y; c[4 * q + 2] = v.z; c[4 * q + 3] = v.w;
    }
    float hk;
#define GETC(d) (c[d])
    NP_PAIRWISE_SQ64(GETC, hk);
#undef GETC
    h[k] = hk;
#pragma unroll
    for (int b = 0; b < 8; ++b) {
        uint4 uh, ul;
        unsigned uhv[4], ulv[4];
#pragma unroll
        for (int e = 0; e < 4; ++e) {
            float x0 = -2.0f * c[b * 8 + e * 2 + 0];
            float x1 = -2.0f * c[b * 8 + e * 2 + 1];
            unsigned short h0 = f2bf_rne(x0), h1 = f2bf_rne(x1);
            unsigned short l0 = f2bf_rne(x0 - bf2f(h0)), l1 = f2bf_rne(x1 - bf2f(h1));
            uhv[e] = (unsigned)h0 | ((unsigned)h1 << 16);
            ulv[e] = (unsigned)l0 | ((unsigned)l1 << 16);
        }
        uh = make_uint4(uhv[0], uhv[1], uhv[2], uhv[3]);
        ul = make_uint4(ulv[0], ulv[1], ulv[2], ulv[3]);
        *(uint4*)(ch + k * 64 + b * 8) = uh;
        *(uint4*)(cl + k * 64 + b * 8) = ul;
    }
}

// Kernel 1: MFMA screen. Block = 512 thr (8 waves), 256 tokens/block
// (32/wave = 2 column-tiles). Streams 16 chunks of 64 codes, double-buffered,
// XOR-swizzled LDS subtiles. acc preloaded with h -> acc = h - 2*dot.
// Writes idx as float to out; negative = ambiguous (needs exact rescue).
__global__ __launch_bounds__(512) void vq_screen(
    const float*          __restrict__ ze,
    const unsigned short* __restrict__ ch_g,
    const unsigned short* __restrict__ cl_g,
    const float*          __restrict__ h_g,
    float*                __restrict__ out) {
    __shared__ __align__(16) char lds[2 * 16384 + 2 * 256];
    const int tid  = threadIdx.x;
    const int lane = tid & 63;
    const int wid  = tid >> 6;
    const int col  = lane & 15;
    const int grp  = lane >> 4;
    const int tbase = blockIdx.x * 256 + wid * 32;

    // --- z fragments (B-operand): lane holds z[tok=col][k=s*32+grp*8 .. +7]
    bf16x8 zh[2][2], zl[2][2];
#pragma unroll
    for (int tt = 0; tt < 2; ++tt)
#pragma unroll
        for (int s = 0; s < 2; ++s) {
            const float* zp = ze + (size_t)(tbase + tt * 16 + col) * 64 + s * 32 + grp * 8;
            float4 v0 = *(const float4*)(zp);
            float4 v1 = *(const float4*)(zp + 4);
            float zv[8] = {v0.x, v0.y, v0.z, v0.w, v1.x, v1.y, v1.z, v1.w};
            bf16x8 hfr, lfr;
#pragma unroll
            for (int j = 0; j < 8; ++j) {
                unsigned short hb = f2bf_rne(zv[j]);
                unsigned short lb = f2bf_rne(zv[j] - bf2f(hb));
                hfr[j] = (short)hb;
                lfr[j] = (short)lb;
            }
            zh[tt][s] = hfr;
            zl[tt][s] = lfr;
        }

    float m1[2] = {INFINITY, INFINITY}, m2[2] = {INFINITY, INFINITY};
    int   ki[2] = {0, 0};

    // --- staging: 64-code chunk -> swizzled LDS subtiles (16 codes x 128 B)
#define STAGE(cc, b)                                                            \
    do {                                                                        \
        int i = tid;                                                            \
        int4 va = *(const int4*)((const char*)ch_g + (cc) * 8192 + i * 16);     \
        int4 vb = *(const int4*)((const char*)cl_g + (cc) * 8192 + i * 16);     \
        int r = i >> 3, slot = i & 7;                                           \
        int st = r >> 4, row = r & 15;                                          \
        int off = (b) * 16384 + st * 2048 + row * 128 + ((slot ^ (row & 7)) << 4); \
        *(int4*)(lds + off) = va;                                               \
        *(int4*)(lds + off + 8192) = vb;                                        \
        if (i < 64) *(float*)(lds + 32768 + (b) * 256 + i * 4) = h_g[(cc) * 64 + i]; \
    } while (0)

    STAGE(0, 0);
    __syncthreads();

    for (int cc = 0; cc < 16; ++cc) {
        int b = cc & 1;
        if (cc + 1 < 16) STAGE(cc + 1, b ^ 1);

        for (int ct = 0; ct < 4; ++ct) {
            // A-frags: lane supplies code row=col, dims k=s*32+grp*8..+7
            const int arow = b * 16384 + ct * 2048 + col * 128;
            bf16x8 ach0 = *(const bf16x8*)(lds + arow + ((((0 * 4) + grp) ^ (col & 7)) << 4));
            bf16x8 ach1 = *(const bf16x8*)(lds + arow + ((((1 * 4) + grp) ^ (col & 7)) << 4));
            bf16x8 acl0 = *(const bf16x8*)(lds + arow + 8192 + ((((0 * 4) + grp) ^ (col & 7)) << 4));
            bf16x8 acl1 = *(const bf16x8*)(lds + arow + 8192 + ((((1 * 4) + grp) ^ (col & 7)) << 4));
            f32x4 hv = *(const f32x4*)(lds + 32768 + b * 256 + ct * 64 + grp * 16);

            f32x4 acc0 = hv, acc1 = hv;
            acc0 = __builtin_amdgcn_mfma_f32_16x16x32_bf16(ach0, zh[0][0], acc0, 0, 0, 0);
            acc1 = __builtin_amdgcn_mfma_f32_16x16x32_bf16(ach0, zh[1][0], acc1, 0, 0, 0);
            acc0 = __builtin_amdgcn_mfma_f32_16x16x32_bf16(ach1, zh[0][1], acc0, 0, 0, 0);
            acc1 = __builtin_amdgcn_mfma_f32_16x16x32_bf16(ach1, zh[1][1], acc1, 0, 0, 0);
            acc0 = __builtin_amdgcn_mfma_f32_16x16x32_bf16(ach0, zl[0][0], acc0, 0, 0, 0);
            acc1 = __builtin_amdgcn_mfma_f32_16x16x32_bf16(ach0, zl[1][0], acc1, 0, 0, 0);
            acc0 = __builtin_amdgcn_mfma_f32_16x16x32_bf16(ach1, zl[0][1], acc0, 0, 0, 0);
            acc1 = __builtin_amdgcn_mfma_f32_16x16x32_bf16(ach1, zl[1][1], acc1, 0, 0, 0);
            acc0 = __builtin_amdgcn_mfma_f32_16x16x32_bf16(acl0, zh[0][0], acc0, 0, 0, 0);
            acc1 = __builtin_amdgcn_mfma_f32_16x16x32_bf16(acl0, zh[1][0], acc1, 0, 0, 0);
            acc0 = __builtin_amdgcn_mfma_f32_16x16x32_bf16(acl1, zh[0][1], acc0, 0, 0, 0);
            acc1 = __builtin_amdgcn_mfma_f32_16x16x32_bf16(acl1, zh[1][1], acc1, 0, 0, 0);

            const int kb = cc * 64 + ct * 16 + grp * 4;
#pragma unroll
            for (int j = 0; j < 4; ++j) {
                float s0 = acc0[j], s1 = acc1[j];
                bool lt0 = s0 < m1[0], lt1 = s1 < m1[1];
                m2[0] = fminf(m2[0], fmaxf(s0, m1[0]));
                m2[1] = fminf(m2[1], fmaxf(s1, m1[1]));
                ki[0] = lt0 ? (kb + j) : ki[0];
                ki[1] = lt1 ? (kb + j) : ki[1];
                m1[0] = fminf(m1[0], s0);
                m1[1] = fminf(m1[1], s1);
            }
        }
        __syncthreads();
    }

    // cross-lane-group reduce (groups hold disjoint code rows of same token col)
#pragma unroll
    for (int d = 16; d <= 32; d <<= 1) {
#pragma unroll
        for (int tt = 0; tt < 2; ++tt) {
            float om1 = __shfl_xor(m1[tt], d, 64);
            float om2 = __shfl_xor(m2[tt], d, 64);
            int   oki = __shfl_xor(ki[tt], d, 64);
            m2[tt] = fminf(fminf(m2[tt], om2), fmaxf(m1[tt], om1));
            ki[tt] = (om1 < m1[tt]) ? oki : ki[tt];
            m1[tt] = fminf(m1[tt], om1);
        }
    }
    if (lane < 16) {
#pragma unroll
        for (int tt = 0; tt < 2; ++tt) {
            int t = tbase + tt * 16 + lane;
            bool flag = (m2[tt] - m1[tt]) < EPS_FLAG;
            out[OUT_IDX + t] = flag ? -(float)(ki[tt] + 1) : (float)ki[tt];
        }
    }
}

// Kernel 2: exact rescue for flagged tokens. One wave per token (strided);
// full 1024-code scan with the round-2 np-exact formula; lexicographic (d,k).
__global__ __launch_bounds__(256) void vq_rescue(
    const float* __restrict__ ze, const float* __restrict__ cb,
    const float* __restrict__ h_g, float* __restrict__ out) {
    const int gw   = (blockIdx.x * 256 + threadIdx.x) >> 6;   // 0..2047
    const int lane = threadIdx.x & 63;
    for (int t = gw; t < NTOK; t += 2048) {
        float f = out[OUT_IDX + t];
        if (!(f < 0.0f)) continue;

        float z[64];
        const float4* zp4 = (const float4*)(ze + (size_t)t * DIM);
#pragma unroll
        for (int q = 0; q < 16; ++q) {
            float4 v = zp4[q];
            z[4 * q] = v.x; z[4 * q + 1] = v.y; z[4 * q + 2] = v.z; z[4 * q + 3] = v.w;
        }
        float sz;
#define GETZ(d) (z[d])
        NP_PAIRWISE_SQ64(GETZ, sz);
#undef GETZ

        float dbest = INFINITY; int kbest = 0;
        for (int q = 0; q < 16; ++q) {
            int k = lane * 16 + q;
            const float4* c4 = (const float4*)(cb + k * DIM);
            float a0 = 0.f, a1 = 0.f, a2 = 0.f, a3 = 0.f;
#pragma unroll
            for (int qq = 0; qq < 16; ++qq) {
                float4 cv = c4[qq];
                a0 = fmaf(cv.x, z[4 * qq + 0], a0);
                a1 = fmaf(cv.y, z[4 * qq + 1], a1);
                a2 = fmaf(cv.z, z[4 * qq + 2], a2);
                a3 = fmaf(cv.w, z[4 * qq + 3], a3);
            }
            float dot = (a0 + a1) + (a2 + a3);
            float dk = (sz + h_g[k]) - 2.0f * dot;
            if (dk < dbest) { dbest = dk; kbest = k; }
        }
        unsigned long long key =
            ((unsigned long long)__float_as_uint(dbest) << 32) | (unsigned)kbest;
#pragma unroll
        for (int d = 1; d < 64; d <<= 1) {
            unsigned long long o = __shfl_xor(key, d, 64);
            if (o < key) key = o;
        }
        if (lane == 0) out[OUT_IDX + t] = (float)(unsigned)(key & 0xFFFFFFFFull);
    }
}

// Kernel 3: gather z_q_st, fp64 SSE, histogram (reads FINAL idx from out).
__global__ __launch_bounds__(256) void vq_gather(
    const float* __restrict__ ze, const float* __restrict__ cb,
    float* __restrict__ out, double* __restrict__ sse_g, int* __restrict__ counts) {
    const int base = blockIdx.x * 256 + threadIdx.x;
    const int stride = 2048 * 256;
    double lsse = 0.0;
#pragma unroll
    for (int it = 0; it < 16; ++it) {
        int gid = base + it * stride;
        int n = gid >> 6, d = gid & 63;
        int idx = (int)out[OUT_IDX + n];
        float q = cb[idx * DIM + d];
        float zv = ze[gid];
        out[gid] = q;
        if (d == 0) atomicAdd(&counts[idx], 1);
        double diff = (double)q - (double)zv;
        lsse = fma(diff, diff, lsse);
    }
#pragma unroll
    for (int off = 32; off > 0; off >>= 1)
        lsse += __shfl_down(lsse, off, 64);
    __shared__ double red[4];
    if ((threadIdx.x & 63) == 0) red[threadIdx.x >> 6] = lsse;
    __syncthreads();
    if (threadIdx.x == 0)
        atomicAdd(sse_g, (red[0] + red[1]) + (red[2] + red[3]));
}

// Kernel 4: finalize loss (= 1.25*MSE) and perplexity.
__global__ void vq_finalize(const double* __restrict__ sse_g,
                            const int* __restrict__ counts,
                            float* __restrict__ out) {
    __shared__ double red[256];
    int tid = threadIdx.x;
    double local = 0.0;
    for (int k = tid; k < NEMB; k += 256) {
        double p = (double)counts[k] / (double)NTOK;
        local += p * log(p + 1e-10);
    }
    red[tid] = local;
    __syncthreads();
    for (int s = 128; s > 0; s >>= 1) {
        if (tid < s) red[tid] += red[tid + s];
        __syncthreads();
    }
    if (tid == 0) {
        double mse = *sse_g / ((double)NTOK * (double)DIM);
        out[OUT_LOSS] = (float)(1.25 * mse);
        out[OUT_PERP] = (float)exp(-red[0]);
    }
}

extern "C" void kernel_launch(void* const* d_in, const int* in_sizes, int n_in,
                              void* d_out, int out_size, void* d_ws, size_t ws_size,
                              hipStream_t stream) {
    const float* ze = (const float*)d_in[0];
    const float* cb = (const float*)d_in[1];
    float* out = (float*)d_out;

    char* w = (char*)d_ws;
    double*         sse    = (double*)w;                    // 8 B @0
    int*            counts = (int*)(w + 64);                // 4 KiB @64
    float*          h      = (float*)(w + 4160);            // 4 KiB @4160
    unsigned short* ch     = (unsigned short*)(w + 8256);   // 128 KiB
    unsigned short* cl     = (unsigned short*)(w + 139328); // 128 KiB

    hipMemsetAsync((void*)w, 0, 4160, stream);  // sse + counts

    vq_prep<<<NEMB / 256, 256, 0, stream>>>(cb, h, ch, cl);
    vq_screen<<<NTOK / 256, 512, 0, stream>>>(ze, ch, cl, h, out);
    vq_rescue<<<512, 256, 0, stream>>>(ze, cb, h, out);
    vq_gather<<<2048, 256, 0, stream>>>(ze, cb, out, sse, counts);
    vq_finalize<<<1, 256, 0, stream>>>(sse, counts, out);
}

// Round 4
// 246.890 us; speedup vs baseline: 1.7404x; 1.2575x over previous
//
#include <hip/hip_runtime.h>
#include <math.h>

// VectorQuantizer: N=131072 tokens, K=1024 codes, D=64, fp32.
// Out layout (flat): z_q_st[N*D] | loss | perplexity | indices[N] (as f32)
#define NTOK 131072
#define NEMB 1024
#define DIM  64
#define OUT_LOSS (NTOK * DIM)
#define OUT_PERP (OUT_LOSS + 1)
#define OUT_IDX  (OUT_LOSS + 2)

#define EPS_FLAG 6e-5f   // screen ambiguity margin (2.3x over derived error bound)

typedef short bf16x8 __attribute__((ext_vector_type(8)));
typedef float f32x4  __attribute__((ext_vector_type(4)));

// ---- numpy fp32 semantics helpers (frozen from round 2 -- PASSED) ----------
__device__ __forceinline__ float sqb(float x) {
    float y = x * x;
    asm volatile("" : "+v"(y));
    return y;
}
// numpy pairwise_sum for n=64 contiguous: 8 accumulators stride 8, then
// ((r0+r1)+(r2+r3))+((r4+r5)+(r6+r7)).
#define NP_PAIRWISE_SQ64(GET, RES)                                     \
    do {                                                               \
        float r0 = sqb(GET(0)), r1 = sqb(GET(1)), r2 = sqb(GET(2)),    \
              r3 = sqb(GET(3)), r4 = sqb(GET(4)), r5 = sqb(GET(5)),    \
              r6 = sqb(GET(6)), r7 = sqb(GET(7));                      \
        _Pragma("unroll")                                              \
        for (int i = 8; i < 64; i += 8) {                              \
            r0 += sqb(GET(i + 0)); r1 += sqb(GET(i + 1));              \
            r2 += sqb(GET(i + 2)); r3 += sqb(GET(i + 3));              \
            r4 += sqb(GET(i + 4)); r5 += sqb(GET(i + 5));              \
            r6 += sqb(GET(i + 6)); r7 += sqb(GET(i + 7));              \
        }                                                              \
        RES = ((r0 + r1) + (r2 + r3)) + ((r4 + r5) + (r6 + r7));       \
    } while (0)

__device__ __forceinline__ unsigned short f2bf_rne(float x) {
    unsigned u = __float_as_uint(x);
    u += 0x7FFFu + ((u >> 16) & 1u);   // round-to-nearest-even
    return (unsigned short)(u >> 16);
}
__device__ __forceinline__ float bf2f(unsigned short b) {
    return __uint_as_float(((unsigned)b) << 16);
}

// ws layout (bytes):
//   0:      sse double
//   64:     counts int[1024]
//   4160:   qcount int            (memset covers 0..4164)
//   4224:   h float[1024]
//   8320:   ch bf16[1024*64]
//   139392: cl bf16[1024*64]
//   270464: qlist int[NTOK]

// Kernel 0: h[k] np-exact; ch/cl = bf16 2-way split of (-2*codebook).
__global__ void vq_prep(const float* __restrict__ cb, float* __restrict__ h,
                        unsigned short* __restrict__ ch, unsigned short* __restrict__ cl) {
    int k = blockIdx.x * 256 + threadIdx.x;
    if (k >= NEMB) return;
    float c[64];
    const float4* p = (const float4*)(cb + k * DIM);
#pragma unroll
    for (int q = 0; q < 16; ++q) {
        float4 v = p[q];
        c[4 * q] = v.x; c[4 * q + 1] = v.y; c[4 * q + 2] = v.z; c[4 * q + 3] = v.w;
    }
    float hk;
#define GETC(d) (c[d])
    NP_PAIRWISE_SQ64(GETC, hk);
#undef GETC
    h[k] = hk;
#pragma unroll
    for (int b = 0; b < 8; ++b) {
        unsigned uhv[4], ulv[4];
#pragma unroll
        for (int e = 0; e < 4; ++e) {
            float x0 = -2.0f * c[b * 8 + e * 2 + 0];
            float x1 = -2.0f * c[b * 8 + e * 2 + 1];
            unsigned short h0 = f2bf_rne(x0), h1 = f2bf_rne(x1);
            unsigned short l0 = f2bf_rne(x0 - bf2f(h0)), l1 = f2bf_rne(x1 - bf2f(h1));
            uhv[e] = (unsigned)h0 | ((unsigned)h1 << 16);
            ulv[e] = (unsigned)l0 | ((unsigned)l1 << 16);
        }
        *(uint4*)(ch + k * 64 + b * 8) = make_uint4(uhv[0], uhv[1], uhv[2], uhv[3]);
        *(uint4*)(cl + k * 64 + b * 8) = make_uint4(ulv[0], ulv[1], ulv[2], ulv[3]);
    }
}

// Kernel 1: MFMA screen (frozen numerics from round 3 -- PASSED).
// Writes screened idx for every token; appends ambiguous tokens to qlist.
__global__ __launch_bounds__(512) void vq_screen(
    const float*          __restrict__ ze,
    const unsigned short* __restrict__ ch_g,
    const unsigned short* __restrict__ cl_g,
    const float*          __restrict__ h_g,
    float*                __restrict__ out,
    int*                  __restrict__ qcount,
    int*                  __restrict__ qlist) {
    __shared__ __align__(16) char lds[2 * 16384 + 2 * 256];
    const int tid  = threadIdx.x;
    const int lane = tid & 63;
    const int wid  = tid >> 6;
    const int col  = lane & 15;
    const int grp  = lane >> 4;
    const int tbase = blockIdx.x * 256 + wid * 32;

    // z fragments (B-operand): lane holds z[tok=col][k=s*32+grp*8 .. +7]
    bf16x8 zh[2][2], zl[2][2];
#pragma unroll
    for (int tt = 0; tt < 2; ++tt)
#pragma unroll
        for (int s = 0; s < 2; ++s) {
            const float* zp = ze + (size_t)(tbase + tt * 16 + col) * 64 + s * 32 + grp * 8;
            float4 v0 = *(const float4*)(zp);
            float4 v1 = *(const float4*)(zp + 4);
            float zv[8] = {v0.x, v0.y, v0.z, v0.w, v1.x, v1.y, v1.z, v1.w};
            bf16x8 hfr, lfr;
#pragma unroll
            for (int j = 0; j < 8; ++j) {
                unsigned short hb = f2bf_rne(zv[j]);
                unsigned short lb = f2bf_rne(zv[j] - bf2f(hb));
                hfr[j] = (short)hb;
                lfr[j] = (short)lb;
            }
            zh[tt][s] = hfr;
            zl[tt][s] = lfr;
        }

    float m1[2] = {INFINITY, INFINITY}, m2[2] = {INFINITY, INFINITY};
    int   ki[2] = {0, 0};

#define STAGE(cc, b)                                                            \
    do {                                                                        \
        int i = tid;                                                            \
        int4 va = *(const int4*)((const char*)ch_g + (cc) * 8192 + i * 16);     \
        int4 vb = *(const int4*)((const char*)cl_g + (cc) * 8192 + i * 16);     \
        int r = i >> 3, slot = i & 7;                                           \
        int st = r >> 4, row = r & 15;                                          \
        int off = (b) * 16384 + st * 2048 + row * 128 + ((slot ^ (row & 7)) << 4); \
        *(int4*)(lds + off) = va;                                               \
        *(int4*)(lds + off + 8192) = vb;                                        \
        if (i < 64) *(float*)(lds + 32768 + (b) * 256 + i * 4) = h_g[(cc) * 64 + i]; \
    } while (0)

    STAGE(0, 0);
    __syncthreads();

    for (int cc = 0; cc < 16; ++cc) {
        int b = cc & 1;
        if (cc + 1 < 16) STAGE(cc + 1, b ^ 1);

        for (int ct = 0; ct < 4; ++ct) {
            const int arow = b * 16384 + ct * 2048 + col * 128;
            bf16x8 ach0 = *(const bf16x8*)(lds + arow + ((((0 * 4) + grp) ^ (col & 7)) << 4));
            bf16x8 ach1 = *(const bf16x8*)(lds + arow + ((((1 * 4) + grp) ^ (col & 7)) << 4));
            bf16x8 acl0 = *(const bf16x8*)(lds + arow + 8192 + ((((0 * 4) + grp) ^ (col & 7)) << 4));
            bf16x8 acl1 = *(const bf16x8*)(lds + arow + 8192 + ((((1 * 4) + grp) ^ (col & 7)) << 4));
            f32x4 hv = *(const f32x4*)(lds + 32768 + b * 256 + ct * 64 + grp * 16);

            f32x4 acc0 = hv, acc1 = hv;
            acc0 = __builtin_amdgcn_mfma_f32_16x16x32_bf16(ach0, zh[0][0], acc0, 0, 0, 0);
            acc1 = __builtin_amdgcn_mfma_f32_16x16x32_bf16(ach0, zh[1][0], acc1, 0, 0, 0);
            acc0 = __builtin_amdgcn_mfma_f32_16x16x32_bf16(ach1, zh[0][1], acc0, 0, 0, 0);
            acc1 = __builtin_amdgcn_mfma_f32_16x16x32_bf16(ach1, zh[1][1], acc1, 0, 0, 0);
            acc0 = __builtin_amdgcn_mfma_f32_16x16x32_bf16(ach0, zl[0][0], acc0, 0, 0, 0);
            acc1 = __builtin_amdgcn_mfma_f32_16x16x32_bf16(ach0, zl[1][0], acc1, 0, 0, 0);
            acc0 = __builtin_amdgcn_mfma_f32_16x16x32_bf16(ach1, zl[0][1], acc0, 0, 0, 0);
            acc1 = __builtin_amdgcn_mfma_f32_16x16x32_bf16(ach1, zl[1][1], acc1, 0, 0, 0);
            acc0 = __builtin_amdgcn_mfma_f32_16x16x32_bf16(acl0, zh[0][0], acc0, 0, 0, 0);
            acc1 = __builtin_amdgcn_mfma_f32_16x16x32_bf16(acl0, zh[1][0], acc1, 0, 0, 0);
            acc0 = __builtin_amdgcn_mfma_f32_16x16x32_bf16(acl1, zh[0][1], acc0, 0, 0, 0);
            acc1 = __builtin_amdgcn_mfma_f32_16x16x32_bf16(acl1, zh[1][1], acc1, 0, 0, 0);

            const int kb = cc * 64 + ct * 16 + grp * 4;
#pragma unroll
            for (int j = 0; j < 4; ++j) {
                float s0 = acc0[j], s1 = acc1[j];
                bool lt0 = s0 < m1[0], lt1 = s1 < m1[1];
                m2[0] = fminf(m2[0], fmaxf(s0, m1[0]));
                m2[1] = fminf(m2[1], fmaxf(s1, m1[1]));
                ki[0] = lt0 ? (kb + j) : ki[0];
                ki[1] = lt1 ? (kb + j) : ki[1];
                m1[0] = fminf(m1[0], s0);
                m1[1] = fminf(m1[1], s1);
            }
        }
        __syncthreads();
    }

#pragma unroll
    for (int d = 16; d <= 32; d <<= 1) {
#pragma unroll
        for (int tt = 0; tt < 2; ++tt) {
            float om1 = __shfl_xor(m1[tt], d, 64);
            float om2 = __shfl_xor(m2[tt], d, 64);
            int   oki = __shfl_xor(ki[tt], d, 64);
            m2[tt] = fminf(fminf(m2[tt], om2), fmaxf(m1[tt], om1));
            ki[tt] = (om1 < m1[tt]) ? oki : ki[tt];
            m1[tt] = fminf(m1[tt], om1);
        }
    }
    if (lane < 16) {
#pragma unroll
        for (int tt = 0; tt < 2; ++tt) {
            int t = tbase + tt * 16 + lane;
            out[OUT_IDX + t] = (float)ki[tt];
            if (m2[tt] - m1[tt] < EPS_FLAG) {
                int slot = atomicAdd(qcount, 1);
                qlist[slot] = t;
            }
        }
    }
}

// Kernel 2: exact rescue over the compacted worklist only. One wave per
// queued token; frozen np-exact formula; lexicographic (d,k) min.
__global__ __launch_bounds__(256) void vq_rescue(
    const float* __restrict__ ze, const float* __restrict__ cb,
    const float* __restrict__ h_g, const int* __restrict__ qcount,
    const int* __restrict__ qlist, float* __restrict__ out) {
    const int nq   = *qcount;
    const int gw   = (blockIdx.x * 256 + threadIdx.x) >> 6;   // global wave id
    const int lane = threadIdx.x & 63;
    const int nw   = gridDim.x * 4;                            // total waves

    for (int i = gw; i < nq; i += nw) {
        const int t = qlist[i];

        float z[64];
        const float4* zp4 = (const float4*)(ze + (size_t)t * DIM);
#pragma unroll
        for (int q = 0; q < 16; ++q) {
            float4 v = zp4[q];
            z[4 * q] = v.x; z[4 * q + 1] = v.y; z[4 * q + 2] = v.z; z[4 * q + 3] = v.w;
        }
        float sz;
#define GETZ(d) (z[d])
        NP_PAIRWISE_SQ64(GETZ, sz);
#undef GETZ

        float dbest = INFINITY; int kbest = 0;
        for (int q = 0; q < 16; ++q) {
            int k = lane * 16 + q;
            const float4* c4 = (const float4*)(cb + k * DIM);
            float a0 = 0.f, a1 = 0.f, a2 = 0.f, a3 = 0.f;
#pragma unroll
            for (int qq = 0; qq < 16; ++qq) {
                float4 cv = c4[qq];
                a0 = fmaf(cv.x, z[4 * qq + 0], a0);
                a1 = fmaf(cv.y, z[4 * qq + 1], a1);
                a2 = fmaf(cv.z, z[4 * qq + 2], a2);
                a3 = fmaf(cv.w, z[4 * qq + 3], a3);
            }
            float dot = (a0 + a1) + (a2 + a3);
            float dk = (sz + h_g[k]) - 2.0f * dot;
            if (dk < dbest) { dbest = dk; kbest = k; }
        }
        unsigned long long key =
            ((unsigned long long)__float_as_uint(dbest) << 32) | (unsigned)kbest;
#pragma unroll
        for (int d = 1; d < 64; d <<= 1) {
            unsigned long long o = __shfl_xor(key, d, 64);
            if (o < key) key = o;
        }
        if (lane == 0) out[OUT_IDX + t] = (float)(unsigned)(key & 0xFFFFFFFFull);
    }
}

// Kernel 3: gather z_q_st, fp64 SSE, histogram (reads FINAL idx from out).
__global__ __launch_bounds__(256) void vq_gather(
    const float* __restrict__ ze, const float* __restrict__ cb,
    float* __restrict__ out, double* __restrict__ sse_g, int* __restrict__ counts) {
    const int base = blockIdx.x * 256 + threadIdx.x;
    const int stride = 2048 * 256;
    double lsse = 0.0;
#pragma unroll
    for (int it = 0; it < 16; ++it) {
        int gid = base + it * stride;
        int n = gid >> 6, d = gid & 63;
        int idx = (int)out[OUT_IDX + n];
        float q = cb[idx * DIM + d];
        float zv = ze[gid];
        out[gid] = q;
        if (d == 0) atomicAdd(&counts[idx], 1);
        double diff = (double)q - (double)zv;
        lsse = fma(diff, diff, lsse);
    }
#pragma unroll
    for (int off = 32; off > 0; off >>= 1)
        lsse += __shfl_down(lsse, off, 64);
    __shared__ double red[4];
    if ((threadIdx.x & 63) == 0) red[threadIdx.x >> 6] = lsse;
    __syncthreads();
    if (threadIdx.x == 0)
        atomicAdd(sse_g, (red[0] + red[1]) + (red[2] + red[3]));
}

// Kernel 4: finalize loss (= 1.25*MSE) and perplexity.
__global__ void vq_finalize(const double* __restrict__ sse_g,
                            const int* __restrict__ counts,
                            float* __restrict__ out) {
    __shared__ double red[256];
    int tid = threadIdx.x;
    double local = 0.0;
    for (int k = tid; k < NEMB; k += 256) {
        double p = (double)counts[k] / (double)NTOK;
        local += p * log(p + 1e-10);
    }
    red[tid] = local;
    __syncthreads();
    for (int s = 128; s > 0; s >>= 1) {
        if (tid < s) red[tid] += red[tid + s];
        __syncthreads();
    }
    if (tid == 0) {
        double mse = *sse_g / ((double)NTOK * (double)DIM);
        out[OUT_LOSS] = (float)(1.25 * mse);
        out[OUT_PERP] = (float)exp(-red[0]);
    }
}

extern "C" void kernel_launch(void* const* d_in, const int* in_sizes, int n_in,
                              void* d_out, int out_size, void* d_ws, size_t ws_size,
                              hipStream_t stream) {
    const float* ze = (const float*)d_in[0];
    const float* cb = (const float*)d_in[1];
    float* out = (float*)d_out;

    char* w = (char*)d_ws;
    double*         sse    = (double*)w;                    // @0
    int*            counts = (int*)(w + 64);                // @64   (4 KiB)
    int*            qcount = (int*)(w + 4160);              // @4160 (4 B)
    float*          h      = (float*)(w + 4224);            // @4224 (4 KiB)
    unsigned short* ch     = (unsigned short*)(w + 8320);   // 128 KiB
    unsigned short* cl     = (unsigned short*)(w + 139392); // 128 KiB
    int*            qlist  = (int*)(w + 270464);            // 512 KiB

    // Zero sse + counts + qcount every launch.
    hipMemsetAsync((void*)w, 0, 4164, stream);

    vq_prep<<<NEMB / 256, 256, 0, stream>>>(cb, h, ch, cl);
    vq_screen<<<NTOK / 256, 512, 0, stream>>>(ze, ch, cl, h, out, qcount, qlist);
    vq_rescue<<<512, 256, 0, stream>>>(ze, cb, h, qcount, qlist, out);
    vq_gather<<<2048, 256, 0, stream>>>(ze, cb, out, sse, counts);
    vq_finalize<<<1, 256, 0, stream>>>(sse, counts, out);
}